// Round 1
// baseline (2384.168 us; speedup 1.0000x reference)
//
#include <hip/hip_runtime.h>
#include <cstddef>

#define B_ 2
#define S_ 2048
#define E_ 768
#define H_ 12
#define D_ 64
#define M_ (B_*S_)   // 4096 rows of x

typedef float f4 __attribute__((ext_vector_type(4)));

// ---------------------------------------------------------------------------
// GEMM: out = A[M,768] @ W[768,768] + bias.
// PERM=true  -> scatter output to [B,H,S,D] layout (for Q/K/V)
// PERM=false -> plain row-major [M,768]
// 64x64 block tile, 256 threads, 4x4 acc per thread, BK=16.
// ---------------------------------------------------------------------------
template<bool PERM>
__global__ __launch_bounds__(256) void gemm_bias_k(
    const float* __restrict__ A, const float* __restrict__ W,
    const float* __restrict__ bias, float* __restrict__ out)
{
    const int K = E_, N = E_;
    __shared__ float As[16][64];   // [k][m] transposed stage
    __shared__ float Ws[16][64];   // [k][n]

    const int t  = threadIdx.x;
    const int tx = t & 15, ty = t >> 4;
    const int m0 = blockIdx.y * 64, n0 = blockIdx.x * 64;

    float acc[4][4] = {};

    for (int k0 = 0; k0 < K; k0 += 16) {
        {   // stage A tile 64(m) x 16(k): each thread one float4 along k
            int m = t >> 2, k4 = t & 3;
            f4 v = *(const f4*)(A + (size_t)(m0 + m) * K + k0 + k4 * 4);
            #pragma unroll
            for (int j = 0; j < 4; ++j) As[k4 * 4 + j][m] = v[j];
        }
        {   // stage W tile 16(k) x 64(n)
            int kk = t >> 4, n4 = t & 15;
            f4 v = *(const f4*)(W + (size_t)(k0 + kk) * N + n0 + n4 * 4);
            *(f4*)&Ws[kk][n4 * 4] = v;
        }
        __syncthreads();
        #pragma unroll
        for (int kk = 0; kk < 16; ++kk) {
            f4 a = *(const f4*)&As[kk][ty * 4];
            f4 b = *(const f4*)&Ws[kk][tx * 4];
            #pragma unroll
            for (int i = 0; i < 4; ++i)
                #pragma unroll
                for (int j = 0; j < 4; ++j)
                    acc[i][j] += a[i] * b[j];
        }
        __syncthreads();
    }

    #pragma unroll
    for (int i = 0; i < 4; ++i) {
        int r = m0 + ty * 4 + i;
        #pragma unroll
        for (int j = 0; j < 4; ++j) {
            int c = n0 + tx * 4 + j;
            float v = acc[i][j] + bias[c];
            if (PERM) {
                int b = r >> 11, s = r & (S_ - 1);
                int h = c >> 6,  d = c & (D_ - 1);
                out[(((size_t)(b * H_ + h) << 11) + s) * D_ + d] = v;
            } else {
                out[(size_t)r * N + c] = v;
            }
        }
    }
}

// ---------------------------------------------------------------------------
// Fused attention for one (b,h), 32 q-rows per block, 256 threads.
// thread t: row r = t>>3 (0..31), slice sl = t&7.
// Pass 1: online (m,l) over all keys (scores recomputed, never stored).
// Pass 2: recompute scores, write softmax weights to global, accumulate P@V.
// K/V tiles staged in LDS with column-rotation swizzle (d4+kk)&15 so the
// strided row reads (kk = jk*8+sl) hit 8 distinct banks (conflict-free b128).
// Q row lives in registers (16 x float4).
// ---------------------------------------------------------------------------
__global__ __launch_bounds__(256) void attn_k(
    const float* __restrict__ Q, const float* __restrict__ Kg,
    const float* __restrict__ V, float* __restrict__ P,
    float* __restrict__ ctx)
{
    __shared__ f4 Ks4[64 * 16];
    __shared__ f4 Vs4[64 * 16];
    __shared__ float Ps[32 * 72];      // stride 72 -> bank (8r+k)%32, 2-way max
    __shared__ float red_m[32][8];
    __shared__ float red_l[32][8];

    const int t  = threadIdx.x;
    const int r  = t >> 3, sl = t & 7;
    const int bh = blockIdx.y;         // b*H+h
    const int q0 = blockIdx.x * 32;
    const float scale = 0.125f;        // 1/sqrt(64)

    // Q row -> registers (lanes sharing r read identical addrs -> L1 broadcast)
    f4 q[16];
    {
        const f4* Qg = (const f4*)(Q + ((size_t)bh * S_ + q0 + r) * D_);
        #pragma unroll
        for (int d4 = 0; d4 < 16; ++d4) q[d4] = Qg[d4];
    }

    float m_t = -3.0e38f, l_t = 0.f;

    // ---- pass 1: online row stats ----
    for (int k0 = 0; k0 < S_; k0 += 64) {
        __syncthreads();
        #pragma unroll
        for (int i = 0; i < 4; ++i) {
            int idx = i * 256 + t;
            int kk = idx >> 4, d4 = idx & 15;
            Ks4[kk * 16 + ((d4 + kk) & 15)] =
                *(const f4*)(Kg + ((size_t)bh * S_ + k0 + kk) * D_ + d4 * 4);
        }
        __syncthreads();
        #pragma unroll
        for (int jk = 0; jk < 8; ++jk) {
            int kk = jk * 8 + sl;
            float s = 0.f;
            #pragma unroll
            for (int d4 = 0; d4 < 16; ++d4) {
                f4 kv = Ks4[kk * 16 + ((d4 + kk) & 15)];
                #pragma unroll
                for (int j = 0; j < 4; ++j) s += q[d4][j] * kv[j];
            }
            s *= scale;
            float m_new = fmaxf(m_t, s);
            l_t = l_t * __expf(m_t - m_new) + __expf(s - m_new);
            m_t = m_new;
        }
    }

    // combine the 8 per-slice partials of each row
    __syncthreads();
    red_m[r][sl] = m_t; red_l[r][sl] = l_t;
    __syncthreads();
    float m_row = -3.0e38f;
    #pragma unroll
    for (int j = 0; j < 8; ++j) m_row = fmaxf(m_row, red_m[r][j]);
    float l_row = 0.f;
    #pragma unroll
    for (int j = 0; j < 8; ++j) l_row += red_l[r][j] * __expf(red_m[r][j] - m_row);
    const float inv_l = 1.f / l_row;

    f4 acc0 = {0.f, 0.f, 0.f, 0.f}, acc1 = {0.f, 0.f, 0.f, 0.f};
    float* Pout = P + ((size_t)bh * S_ + q0) * S_;

    // ---- pass 2: normalized weights + P@V ----
    for (int k0 = 0; k0 < S_; k0 += 64) {
        __syncthreads();
        #pragma unroll
        for (int i = 0; i < 4; ++i) {
            int idx = i * 256 + t;
            int kk = idx >> 4, d4 = idx & 15;
            int sw = kk * 16 + ((d4 + kk) & 15);
            Ks4[sw] = *(const f4*)(Kg + ((size_t)bh * S_ + k0 + kk) * D_ + d4 * 4);
            Vs4[sw] = *(const f4*)(V  + ((size_t)bh * S_ + k0 + kk) * D_ + d4 * 4);
        }
        __syncthreads();
        #pragma unroll
        for (int jk = 0; jk < 8; ++jk) {
            int kk = jk * 8 + sl;
            float s = 0.f;
            #pragma unroll
            for (int d4 = 0; d4 < 16; ++d4) {
                f4 kv = Ks4[kk * 16 + ((d4 + kk) & 15)];
                #pragma unroll
                for (int j = 0; j < 4; ++j) s += q[d4][j] * kv[j];
            }
            s *= scale;
            float p = __expf(s - m_row) * inv_l;
            Ps[r * 72 + kk] = p;
            Pout[(size_t)r * S_ + k0 + kk] = p;
        }
        __syncthreads();
        #pragma unroll
        for (int k = 0; k < 64; ++k) {
            float p = Ps[r * 72 + k];
            f4 va = Vs4[k * 16 + ((2 * sl     + k) & 15)];
            f4 vb = Vs4[k * 16 + ((2 * sl + 1 + k) & 15)];
            acc0 += p * va;
            acc1 += p * vb;
        }
    }

    // ctx in [B,S,E] so the output projection is a plain GEMM
    const int b = bh / H_, h = bh % H_;
    float* cp = ctx + ((size_t)(b * S_ + q0 + r)) * E_ + h * D_ + sl * 8;
    *(f4*)cp       = acc0;
    *(f4*)(cp + 4) = acc1;
}

// ---------------------------------------------------------------------------
extern "C" void kernel_launch(void* const* d_in, const int* in_sizes, int n_in,
                              void* d_out, int out_size, void* d_ws, size_t ws_size,
                              hipStream_t stream) {
    const float* x  = (const float*)d_in[0];
    const float* Wq = (const float*)d_in[1];
    const float* bq = (const float*)d_in[2];
    const float* Wk = (const float*)d_in[3];
    const float* bk = (const float*)d_in[4];
    const float* Wv = (const float*)d_in[5];
    const float* bv = (const float*)d_in[6];
    const float* Wo = (const float*)d_in[7];
    const float* bo = (const float*)d_in[8];

    const size_t NE = (size_t)M_ * E_;      // 3,145,728
    float* Qws = (float*)d_ws;              // [B,H,S,D]
    float* Kws = Qws + NE;
    float* Vws = Kws + NE;
    float* Cws = Vws + NE;                  // ctx [B,S,E]

    float* out0  = (float*)d_out;           // [B,S,E]
    float* attnw = out0 + NE;               // [B,H,S,S]

    dim3 gg(E_ / 64, M_ / 64);              // (12, 64)
    gemm_bias_k<true ><<<gg, 256, 0, stream>>>(x,   Wq, bq, Qws);
    gemm_bias_k<true ><<<gg, 256, 0, stream>>>(x,   Wk, bk, Kws);
    gemm_bias_k<true ><<<gg, 256, 0, stream>>>(x,   Wv, bv, Vws);
    attn_k<<<dim3(S_ / 32, B_ * H_), 256, 0, stream>>>(Qws, Kws, Vws, attnw, Cws);
    gemm_bias_k<false><<<gg, 256, 0, stream>>>(Cws, Wo, bo, out0);
}

// Round 2
// 809.533 us; speedup vs baseline: 2.9451x; 2.9451x over previous
//
#include <hip/hip_runtime.h>
#include <cstddef>

#define B_ 2
#define S_ 2048
#define E_ 768
#define H_ 12
#define D_ 64
#define M_ (B_*S_)   // 4096 rows of x

typedef float f4 __attribute__((ext_vector_type(4)));
typedef short short8 __attribute__((ext_vector_type(8)));

// fp32 -> bf16 (RNE, bit pattern as short)
__device__ __forceinline__ short f2bf(float f) {
    union { float f; unsigned u; } v; v.f = f;
    unsigned r = (v.u + 0x7fffu + ((v.u >> 16) & 1u)) >> 16;
    return (short)r;
}

// ---------------------------------------------------------------------------
// GEMM: out = A[M,768] @ W[768,768] + bias.
// MODE 0: fp32 [M,768]           (output projection)
// MODE 1: bf16 [B,H,S,D] *scale  (Q pre-scaled by 0.125, K scale 1)
// MODE 2: bf16 [B,H,D,S]         (V transposed for PV B-fragments)
// ---------------------------------------------------------------------------
template<int MODE>
__global__ __launch_bounds__(256) void gemm_bias_k(
    const float* __restrict__ A, const float* __restrict__ W,
    const float* __restrict__ bias, float* __restrict__ outf,
    short* __restrict__ outb, float scale)
{
    const int K = E_, N = E_;
    __shared__ float As[16][64];
    __shared__ float Ws[16][64];

    const int t  = threadIdx.x;
    const int tx = t & 15, ty = t >> 4;
    const int m0 = blockIdx.y * 64, n0 = blockIdx.x * 64;

    float acc[4][4] = {};

    for (int k0 = 0; k0 < K; k0 += 16) {
        {
            int m = t >> 2, k4 = t & 3;
            f4 v = *(const f4*)(A + (size_t)(m0 + m) * K + k0 + k4 * 4);
            #pragma unroll
            for (int j = 0; j < 4; ++j) As[k4 * 4 + j][m] = v[j];
        }
        {
            int kk = t >> 4, n4 = t & 15;
            f4 v = *(const f4*)(W + (size_t)(k0 + kk) * N + n0 + n4 * 4);
            *(f4*)&Ws[kk][n4 * 4] = v;
        }
        __syncthreads();
        #pragma unroll
        for (int kk = 0; kk < 16; ++kk) {
            f4 a = *(const f4*)&As[kk][ty * 4];
            f4 b = *(const f4*)&Ws[kk][tx * 4];
            #pragma unroll
            for (int i = 0; i < 4; ++i)
                #pragma unroll
                for (int j = 0; j < 4; ++j)
                    acc[i][j] += a[i] * b[j];
        }
        __syncthreads();
    }

    #pragma unroll
    for (int i = 0; i < 4; ++i) {
        int r = m0 + ty * 4 + i;
        #pragma unroll
        for (int j = 0; j < 4; ++j) {
            int c = n0 + tx * 4 + j;
            float v = acc[i][j] + bias[c];
            if (MODE == 0) {
                outf[(size_t)r * N + c] = v;
            } else {
                int b = r >> 11, s = r & (S_ - 1);
                int h = c >> 6,  d = c & (D_ - 1);
                if (MODE == 1)
                    outb[((size_t)(b * H_ + h) * S_ + s) * D_ + d] = f2bf(v * scale);
                else
                    outb[((size_t)(b * H_ + h) * D_ + d) * S_ + s] = f2bf(v);
            }
        }
    }
}

// ---------------------------------------------------------------------------
// MFMA flash attention. Block = 256 thr (4 waves), 64 q-rows (16/wave), one
// (b,h). Pass 1: QK^T via mfma_f32_16x16x32_bf16, l = sum exp(s-8) (fixed
// base, exact). Pass 2: recompute scores, write normalized P (fp32, the
// required output) and accumulate P@V (P via LDS C->A layout round-trip,
// V from pre-transposed Vt so B-frags are contiguous).
// LDS tiles XOR-swizzled: chunk c of row r at [r][c^(r&7)] -> <=2-way (free).
// ---------------------------------------------------------------------------
__global__ __launch_bounds__(256) void attn_k(
    const short* __restrict__ Qb, const short* __restrict__ Kb,
    const short* __restrict__ Vt, float* __restrict__ P,
    float* __restrict__ ctx)
{
    __shared__ short8 KT[64][8];     // 8 KB, [key][d-chunk] swizzled
    __shared__ short8 VT[64][8];     // 8 KB, [d][key-chunk] swizzled
    __shared__ short  PT[4][16][72]; // per-wave P tile, stride 72 (16B-aligned)

    const int t    = threadIdx.x;
    const int w    = t >> 6;
    const int lane = t & 63, ln = lane & 15, quad = lane >> 4;
    const int bh   = blockIdx.y;
    const int qr   = blockIdx.x * 64 + w * 16;   // wave's first q row

    const size_t kvbase = (size_t)bh * S_ * D_;  // also == bh*D_*S_ for Vt

    // Q A-fragments (Q pre-scaled by 1/8): lane holds Q[qr+ln][quad*8+j (+32)]
    short8 qf0, qf1;
    {
        const short* qrow = Qb + kvbase + (size_t)(qr + ln) * D_;
        qf0 = *(const short8*)(qrow + quad * 8);
        qf1 = *(const short8*)(qrow + 32 + quad * 8);
    }

    f4 l_acc = {0.f, 0.f, 0.f, 0.f};

    // ---- pass 1: l = sum exp(s - 8) ----
    for (int k0 = 0; k0 < S_; k0 += 64) {
        __syncthreads();
        #pragma unroll
        for (int i = 0; i < 2; ++i) {
            int c = t + i * 256, r = c >> 3, cc = c & 7;
            KT[r][cc ^ (r & 7)] =
                *(const short8*)(Kb + kvbase + (size_t)(k0 + r) * D_ + cc * 8);
        }
        __syncthreads();
        #pragma unroll
        for (int kg = 0; kg < 4; ++kg) {
            int row = kg * 16 + ln;
            short8 kf0 = KT[row][quad ^ (row & 7)];
            short8 kf1 = KT[row][(quad + 4) ^ (row & 7)];
            f4 sc = {0.f, 0.f, 0.f, 0.f};
            sc = __builtin_amdgcn_mfma_f32_16x16x32_bf16(qf0, kf0, sc, 0, 0, 0);
            sc = __builtin_amdgcn_mfma_f32_16x16x32_bf16(qf1, kf1, sc, 0, 0, 0);
            #pragma unroll
            for (int g = 0; g < 4; ++g) l_acc[g] += __expf(sc[g] - 8.0f);
        }
    }

    // reduce l over the 16 lanes of each quad (they share rows quad*4+g)
    f4 inv_l;
    #pragma unroll
    for (int g = 0; g < 4; ++g) {
        float v = l_acc[g];
        v += __shfl_xor(v, 1, 64);
        v += __shfl_xor(v, 2, 64);
        v += __shfl_xor(v, 4, 64);
        v += __shfl_xor(v, 8, 64);
        inv_l[g] = 1.0f / v;
    }

    f4 acc[4];
    #pragma unroll
    for (int dg = 0; dg < 4; ++dg) acc[dg] = (f4){0.f, 0.f, 0.f, 0.f};

    float* Pw = P + ((size_t)bh * S_ + qr) * S_;

    // ---- pass 2: normalized P out + P@V ----
    for (int k0 = 0; k0 < S_; k0 += 64) {
        __syncthreads();
        #pragma unroll
        for (int i = 0; i < 2; ++i) {
            int c = t + i * 256, r = c >> 3, cc = c & 7;
            KT[r][cc ^ (r & 7)] =
                *(const short8*)(Kb + kvbase + (size_t)(k0 + r) * D_ + cc * 8);
            VT[r][cc ^ (r & 7)] =
                *(const short8*)(Vt + kvbase + (size_t)r * S_ + k0 + cc * 8);
        }
        __syncthreads();
        #pragma unroll
        for (int kg = 0; kg < 4; ++kg) {
            int row = kg * 16 + ln;
            short8 kf0 = KT[row][quad ^ (row & 7)];
            short8 kf1 = KT[row][(quad + 4) ^ (row & 7)];
            f4 sc = {0.f, 0.f, 0.f, 0.f};
            sc = __builtin_amdgcn_mfma_f32_16x16x32_bf16(qf0, kf0, sc, 0, 0, 0);
            sc = __builtin_amdgcn_mfma_f32_16x16x32_bf16(qf1, kf1, sc, 0, 0, 0);
            #pragma unroll
            for (int g = 0; g < 4; ++g) {
                float p = __expf(sc[g] - 8.0f) * inv_l[g];
                Pw[(size_t)(quad * 4 + g) * S_ + k0 + kg * 16 + ln] = p;
                PT[w][quad * 4 + g][kg * 16 + ln] = f2bf(p);
            }
        }
        __syncthreads();   // make PT visible (also orders vs next staging)
        short8 af0 = *(const short8*)&PT[w][ln][quad * 8];
        short8 af1 = *(const short8*)&PT[w][ln][32 + quad * 8];
        #pragma unroll
        for (int dg = 0; dg < 4; ++dg) {
            int row = dg * 16 + ln;
            short8 vf0 = VT[row][quad ^ (row & 7)];
            short8 vf1 = VT[row][(quad + 4) ^ (row & 7)];
            acc[dg] = __builtin_amdgcn_mfma_f32_16x16x32_bf16(af0, vf0, acc[dg], 0, 0, 0);
            acc[dg] = __builtin_amdgcn_mfma_f32_16x16x32_bf16(af1, vf1, acc[dg], 0, 0, 0);
        }
    }

    // ctx in [B,S,E] so the output projection is a plain GEMM
    const int b = bh / H_, h = bh % H_;
    #pragma unroll
    for (int dg = 0; dg < 4; ++dg)
        #pragma unroll
        for (int g = 0; g < 4; ++g)
            ctx[(size_t)(b * S_ + qr + quad * 4 + g) * E_ + h * D_ + dg * 16 + ln]
                = acc[dg][g];
}

// ---------------------------------------------------------------------------
extern "C" void kernel_launch(void* const* d_in, const int* in_sizes, int n_in,
                              void* d_out, int out_size, void* d_ws, size_t ws_size,
                              hipStream_t stream) {
    const float* x  = (const float*)d_in[0];
    const float* Wq = (const float*)d_in[1];
    const float* bq = (const float*)d_in[2];
    const float* Wk = (const float*)d_in[3];
    const float* bk = (const float*)d_in[4];
    const float* Wv = (const float*)d_in[5];
    const float* bv = (const float*)d_in[6];
    const float* Wo = (const float*)d_in[7];
    const float* bo = (const float*)d_in[8];

    const size_t NE = (size_t)M_ * E_;       // 3,145,728
    short* Qb  = (short*)d_ws;               // bf16 [B,H,S,D], pre-scaled 1/8
    short* Kb  = Qb + NE;                    // bf16 [B,H,S,D]
    short* Vtb = Kb + NE;                    // bf16 [B,H,D,S]
    float* Cws = (float*)(Vtb + NE);         // fp32 ctx [B,S,E]

    float* out0  = (float*)d_out;            // [B,S,E]
    float* attnw = out0 + NE;                // [B,H,S,S]

    dim3 gg(E_ / 64, M_ / 64);               // (12, 64)
    gemm_bias_k<1><<<gg, 256, 0, stream>>>(x, Wq, bq, nullptr, Qb, 0.125f);
    gemm_bias_k<1><<<gg, 256, 0, stream>>>(x, Wk, bk, nullptr, Kb, 1.0f);
    gemm_bias_k<2><<<gg, 256, 0, stream>>>(x, Wv, bv, nullptr, Vtb, 1.0f);
    attn_k<<<dim3(S_ / 64, B_ * H_), 256, 0, stream>>>(Qb, Kb, Vtb, attnw, Cws);
    gemm_bias_k<0><<<gg, 256, 0, stream>>>(Cws, Wo, bo, out0, nullptr, 1.0f);
}